// Round 4
// baseline (330.820 us; speedup 1.0000x reference)
//
#include <hip/hip_runtime.h>
#include <hip/hip_bf16.h>

#define NB 4
#define NS 2048
#define ND 1024
#define NH 16
#define NDH 64
#define E_ 8388608   // NB*NS*ND
#define W_ 1048576   // ND*ND

typedef __attribute__((ext_vector_type(8))) __bf16 bf16x8;
typedef __attribute__((ext_vector_type(4))) float f32x4;
typedef __attribute__((ext_vector_type(2))) unsigned int u32x2;
typedef unsigned short us16;
typedef unsigned int u32;

__device__ __forceinline__ unsigned short f2bf(float f) {
  union { float f; unsigned u; } v; v.f = f;
  unsigned r = v.u + 0x7FFFu + ((v.u >> 16) & 1u);
  return (unsigned short)(r >> 16);
}

typedef const __attribute__((address_space(1))) unsigned int* gas_t;
typedef __attribute__((address_space(3))) unsigned int* las_t;
__device__ __forceinline__ void gl2lds16(const void* g, void* l) {
  __builtin_amdgcn_global_load_lds((gas_t)g, (las_t)l, 16, 0, 0);
}

// ---------------------------------------------------------------------------
// fp32 -> bf16 conversion pass
// ---------------------------------------------------------------------------
__global__ __launch_bounds__(256) void conv_bf16(
    const float* __restrict__ q, const float* __restrict__ k, const float* __restrict__ v,
    const float* __restrict__ wq, const float* __restrict__ wk, const float* __restrict__ wv,
    const float* __restrict__ wo,
    us16* __restrict__ qb, us16* __restrict__ kb, us16* __restrict__ vb,
    us16* __restrict__ wqb, us16* __restrict__ wkb, us16* __restrict__ wvb,
    us16* __restrict__ wob)
{
  int b = blockIdx.x;
  int seg, off;
  if (b < 24576) { seg = b >> 13; off = b & 8191; }
  else { b -= 24576; seg = 3 + (b >> 10); off = b & 1023; }
  const float* s; us16* d;
  switch (seg) {
    case 0: s = q;  d = qb;  break;
    case 1: s = k;  d = kb;  break;
    case 2: s = v;  d = vb;  break;
    case 3: s = wq; d = wqb; break;
    case 4: s = wk; d = wkb; break;
    case 5: s = wv; d = wvb; break;
    default: s = wo; d = wob; break;
  }
  size_t idx = ((size_t)off * 256 + threadIdx.x) * 4;
  float4 f = *(const float4*)(s + idx);
  ushort4 u;
  u.x = f2bf(f.x); u.y = f2bf(f.y); u.z = f2bf(f.z); u.w = f2bf(f.w);
  *(ushort4*)(d + idx) = u;
}

// ---------------------------------------------------------------------------
// Projection GEMM v9: BM=256 BN=128 BK=32, 4 waves (2Mx2N), wave-tile 128x64
// (8x4 frags -> 0.375 KB LDS-read per MFMA, under the ~412 B/MFMA-slot LDS
// pipe capacity that bound the 64x64 tile). 3 LDS buffers (72KB, 2 blk/CU),
// 2 tiles in flight, counted vmcnt(6) (6 gl2lds per stage).
// Bank swizzle for 64B rows: physical slot p = c ^ ((row>>1)&3); bank-group
// g = 4*(row&1)+p -> each 8-lane group hits 8 distinct groups (conflict-free).
// Staged via pre-swizzled GLOBAL source + linear gl2lds dest (rule #21):
// lane L fetches logical slot (L&3)^((L>>3)&3) for row L>>2 of the chunk.
// vmcnt ledger: prologue {0,1}=12 loads -> vmcnt(6) = tile0 landed; iter t
// stages t+2 into buf (t+2)%3 (read at t-1, behind barrier); end-of-iter
// vmcnt(6) = tile t+1 landed (t=30: vmcnt(0); t=31: none).
// seg 0: Q [B,S,D] scaled; seg 1: K [B,S,D]; seg 2: V -> [B,H,DH,S].
// ---------------------------------------------------------------------------
#define STG3(bi, kt) { \
    gl2lds16(gaS + (kt),            &As[bi][w * 64][0]); \
    gl2lds16(gaS + (kt) + 16 * ND,  &As[bi][w * 64 + 16][0]); \
    gl2lds16(gaS + (kt) + 32 * ND,  &As[bi][w * 64 + 32][0]); \
    gl2lds16(gaS + (kt) + 48 * ND,  &As[bi][w * 64 + 48][0]); \
    gl2lds16(gbS + (kt),            &Bs[bi][w * 32][0]); \
    gl2lds16(gbS + (kt) + 16 * ND,  &Bs[bi][w * 32 + 16][0]); }

#define BARX() { __builtin_amdgcn_s_barrier(); \
                 __builtin_amdgcn_sched_barrier(0); \
                 asm volatile("" ::: "memory"); }

#define GEMM_PIPE3() \
  f32x4 acc[8][4] = {}; \
  STG3(0, 0) STG3(1, 32) \
  asm volatile("s_waitcnt vmcnt(6)" ::: "memory"); \
  BARX() \
  _Pragma("unroll") \
  for (int t = 0; t < 32; ++t) { \
    if (t + 2 < 32) STG3((t + 2) % 3, (t + 2) * 32) \
    bf16x8 af[8], bfr[4]; \
    _Pragma("unroll") \
    for (int i = 0; i < 8; ++i) \
      af[i] = *(const bf16x8*)&As[t % 3][wm * 128 + i * 16 + l15][ps]; \
    _Pragma("unroll") \
    for (int j = 0; j < 4; ++j) \
      bfr[j] = *(const bf16x8*)&Bs[t % 3][wn * 64 + j * 16 + l15][ps]; \
    __builtin_amdgcn_s_setprio(1); \
    _Pragma("unroll") \
    for (int i = 0; i < 8; ++i) \
      _Pragma("unroll") \
      for (int j = 0; j < 4; ++j) \
        acc[i][j] = __builtin_amdgcn_mfma_f32_16x16x32_bf16(af[i], bfr[j], acc[i][j], 0, 0, 0); \
    __builtin_amdgcn_s_setprio(0); \
    if (t < 30)       asm volatile("s_waitcnt vmcnt(6)" ::: "memory"); \
    else if (t == 30) asm volatile("s_waitcnt vmcnt(0)" ::: "memory"); \
    if (t < 31) BARX() \
  }

__global__ __launch_bounds__(256, 2) void gemm_proj9(
    const us16* __restrict__ A0, const us16* __restrict__ A1, const us16* __restrict__ A2,
    const us16* __restrict__ W0, const us16* __restrict__ W1, const us16* __restrict__ W2,
    const float* __restrict__ b0, const float* __restrict__ b1, const float* __restrict__ b2,
    us16* __restrict__ o0, us16* __restrict__ o1, us16* __restrict__ o2,
    float qscale, int s0, int s1, int s2)
{
  const int seg = (blockIdx.z == 0) ? s0 : (blockIdx.z == 1) ? s1 : s2;
  const us16* A  = (blockIdx.z == 0) ? A0 : (blockIdx.z == 1) ? A1 : A2;
  const us16* Wt = (blockIdx.z == 0) ? W0 : (blockIdx.z == 1) ? W1 : W2;
  const float* bias = (blockIdx.z == 0) ? b0 : (blockIdx.z == 1) ? b1 : b2;
  us16* out = (blockIdx.z == 0) ? o0 : (blockIdx.z == 1) ? o1 : o2;
  const float scale = (seg == 0) ? qscale : 1.0f;

  __shared__ us16 As[3][256][32];
  __shared__ us16 Bs[3][128][32];
  const int tid = threadIdx.x;
  const int lane = tid & 63;
  const int w = tid >> 6;              // 4 waves
  const int l15 = lane & 15, quad = lane >> 4;
  const int wm = w >> 1, wn = w & 1;   // 2M x 2N
  const int ps = (quad ^ ((l15 >> 1) & 3)) * 8;          // read slot (swizzled)
  const int sr4 = lane >> 2;                              // stage row-in-chunk
  const int sc  = (lane & 3) ^ ((lane >> 3) & 3);         // stage logical slot
  const int rowBase = blockIdx.x * 256, colBase = blockIdx.y * 128;
  const us16* gaS = A  + (size_t)(rowBase + w * 64 + sr4) * ND + sc * 8;
  const us16* gbS = Wt + (size_t)(colBase + w * 32 + sr4) * ND + sc * 8;

  GEMM_PIPE3()

  const int wr = wm * 128, wc = wn * 64;
  if (seg < 2) {
    #pragma unroll
    for (int i = 0; i < 8; ++i) {
      #pragma unroll
      for (int j = 0; j < 4; ++j) {
        int colg = colBase + wc + j * 16 + l15;
        float bval = bias[colg];
        #pragma unroll
        for (int r = 0; r < 4; ++r) {
          int rowg = rowBase + wr + i * 16 + quad * 4 + r;
          out[(size_t)rowg * ND + colg] = f2bf((acc[i][j][r] + bval) * scale);
        }
      }
    }
  } else {
    #pragma unroll
    for (int i = 0; i < 8; ++i) {
      #pragma unroll
      for (int j = 0; j < 4; ++j) {
        int colg = colBase + wc + j * 16 + l15;
        float bval = bias[colg];
        int h_ = colg >> 6, d_ = colg & 63;
        int rowg0 = rowBase + wr + i * 16 + quad * 4;
        int b_ = rowg0 >> 11, sr0 = rowg0 & (NS - 1);
        ushort4 vv;
        vv.x = f2bf(acc[i][j][0] + bval);
        vv.y = f2bf(acc[i][j][1] + bval);
        vv.z = f2bf(acc[i][j][2] + bval);
        vv.w = f2bf(acc[i][j][3] + bval);
        *(ushort4*)(out + ((size_t)(b_ * NH + h_) * NDH + d_) * NS + sr0) = vv;
      }
    }
  }
}

// ---------------------------------------------------------------------------
// Output projection, same structure: out = ctx(bf16) @ wo^T + bo, fp32
// ---------------------------------------------------------------------------
__global__ __launch_bounds__(256, 2) void gemm_out9(
    const us16* __restrict__ A, const us16* __restrict__ Wt,
    const float* __restrict__ bias, float* __restrict__ out)
{
  __shared__ us16 As[3][256][32];
  __shared__ us16 Bs[3][128][32];
  const int tid = threadIdx.x;
  const int lane = tid & 63;
  const int w = tid >> 6;
  const int l15 = lane & 15, quad = lane >> 4;
  const int wm = w >> 1, wn = w & 1;
  const int ps = (quad ^ ((l15 >> 1) & 3)) * 8;
  const int sr4 = lane >> 2;
  const int sc  = (lane & 3) ^ ((lane >> 3) & 3);
  const int rowBase = blockIdx.x * 256, colBase = blockIdx.y * 128;
  const us16* gaS = A  + (size_t)(rowBase + w * 64 + sr4) * ND + sc * 8;
  const us16* gbS = Wt + (size_t)(colBase + w * 32 + sr4) * ND + sc * 8;

  GEMM_PIPE3()

  const int wr = wm * 128, wc = wn * 64;
  #pragma unroll
  for (int i = 0; i < 8; ++i) {
    #pragma unroll
    for (int j = 0; j < 4; ++j) {
      int colg = colBase + wc + j * 16 + l15;
      float bval = bias[colg];
      #pragma unroll
      for (int r = 0; r < 4; ++r) {
        int rowg = rowBase + wr + i * 16 + quad * 4 + r;
        out[(size_t)rowg * ND + colg] = acc[i][j][r] + bval;
      }
    }
  }
}

// ---------------------------------------------------------------------------
// Flash attention, causal, fixed-max softmax (exp2 domain; scale folded in Q).
// KVBLK=128, double-buffered K/V, tile-0 prefetch overlapped with Q staging,
// per-h2 diagonal skip, setprio around MFMA clusters. Unchanged from R1.
// ---------------------------------------------------------------------------
__global__ __launch_bounds__(256, 2) void attn(
    const us16* __restrict__ Qh, const us16* __restrict__ Kh,
    const us16* __restrict__ Vht, us16* __restrict__ ctx)
{
  __shared__ us16 Ks[2][128][64];
  __shared__ us16 Vts[2][64][128];
  __shared__ us16 Ps[4][32][32];
  us16* Qsta = &Vts[1][0][0];

  const int bh = blockIdx.x & 63;
  const int pr = blockIdx.x >> 6;
  const int b_ = bh >> 4, h_ = bh & 15;
  const int tid = threadIdx.x, lane = tid & 63, w = tid >> 6;
  const int l15 = lane & 15, quad = lane >> 4;
  const int sw = l15 & 7;
  const int lr8 = lane >> 3;
  const int cu = (lane & 7) ^ (lr8 & 7);
  const int vr = lane >> 4;
  const int vs = lane & 15;
  const int cs0 = (vs & 8) | ((vs & 7) ^ vr);
  const int cs1 = (vs & 8) | ((vs & 7) ^ (vr | 4));

  bf16x8 ones;
  #pragma unroll
  for (int i = 0; i < 8; ++i) ones[i] = (__bf16)1.0f;

  const us16* gk  = Kh  + ((size_t)b_ * NS + w * 32 + lr8) * ND + h_ * NDH + cu * 8;
  const us16* gv0 = Vht + ((size_t)bh * NDH + w * 16 + vr) * NS + cs0 * 8;
  const us16* gv1 = Vht + ((size_t)bh * NDH + w * 16 + 4 + vr) * NS + cs1 * 8;

  for (int pass = 0; pass < 2; ++pass) {
    const int tq = pass ? (15 - pr) : pr;
    const int qb0 = tq * 128;
    const int nt = tq + 1;
    const int qw = qb0 + w * 32;

    __syncthreads();
    {
      const us16* gq = Qh + ((size_t)b_ * NS + qb0 + w * 32 + lr8) * ND + h_ * NDH + cu * 8;
      #pragma unroll
      for (int u = 0; u < 4; ++u)
        gl2lds16(gq + (size_t)u * 8 * ND, Qsta + (w * 32 + u * 8) * 64);
    }
    #pragma unroll
    for (int u = 0; u < 4; ++u)
      gl2lds16(gk + (size_t)(u * 8) * ND, &Ks[0][w * 32 + u * 8][0]);
    gl2lds16(gv0,          &Vts[0][w * 16][0]);
    gl2lds16(gv1,          &Vts[0][w * 16 + 4][0]);
    gl2lds16(gv0 + 8 * NS, &Vts[0][w * 16 + 8][0]);
    gl2lds16(gv1 + 8 * NS, &Vts[0][w * 16 + 12][0]);
    __syncthreads();
    bf16x8 bq[2][2];
    #pragma unroll
    for (int ntl = 0; ntl < 2; ++ntl)
      #pragma unroll
      for (int c = 0; c < 2; ++c)
        bq[ntl][c] = *(const bf16x8*)(Qsta + (w * 32 + ntl * 16 + l15) * 64 +
                                      (((c * 4 + quad) ^ sw) * 8));

    f32x4 o[2][4] = {};
    f32x4 o_l[2] = {};

    for (int it = 0; it < nt; ++it) {
      const int kb = it * 128;
      const int cur = it & 1;
      __syncthreads();
      if (it + 1 < nt) {
        const int nxt = cur ^ 1;
        const int kn = kb + 128;
        #pragma unroll
        for (int u = 0; u < 4; ++u)
          gl2lds16(gk + (size_t)(kn + u * 8) * ND, &Ks[nxt][w * 32 + u * 8][0]);
        gl2lds16(gv0 + kn,          &Vts[nxt][w * 16][0]);
        gl2lds16(gv1 + kn,          &Vts[nxt][w * 16 + 4][0]);
        gl2lds16(gv0 + kn + 8 * NS, &Vts[nxt][w * 16 + 8][0]);
        gl2lds16(gv1 + kn + 8 * NS, &Vts[nxt][w * 16 + 12][0]);
      }
      #pragma unroll
      for (int h2 = 0; h2 < 4; ++h2) {
        const int keyb0 = kb + h2 * 32;
        if (keyb0 > qw + 31) continue;
        const bool full = (keyb0 + 31 <= qw);
        f32x4 s[2][2];
        __builtin_amdgcn_s_setprio(1);
        #pragma unroll
        for (int mt = 0; mt < 2; ++mt) {
          bf16x8 ak0 = *(const bf16x8*)&Ks[cur][h2 * 32 + mt * 16 + l15][(quad ^ sw) * 8];
          bf16x8 ak1 = *(const bf16x8*)&Ks[cur][h2 * 32 + mt * 16 + l15][((4 + quad) ^ sw) * 8];
          #pragma unroll
          for (int ntl = 0; ntl < 2; ++ntl) {
            f32x4 t = {};
            t = __builtin_amdgcn_mfma_f32_16x16x32_bf16(ak0, bq[ntl][0], t, 0, 0, 0);
            t = __builtin_amdgcn_mfma_f32_16x16x32_bf16(ak1, bq[ntl][1], t, 0, 0, 0);
            s[mt][ntl] = t;
          }
        }
        __builtin_amdgcn_s_setprio(0);
        #pragma unroll
        for (int mt = 0; mt < 2; ++mt)
          #pragma unroll
          for (int ntl = 0; ntl < 2; ++ntl) {
            u32 u[4];
            if (full) {
              #pragma unroll
              for (int r = 0; r < 4; ++r)
                u[r] = __float_as_uint(__builtin_amdgcn_exp2f(s[mt][ntl][r]));
            } else {
              const int keyb = keyb0 + mt * 16 + quad * 4;
              const int qg = qw + ntl * 16 + l15;
              #pragma unroll
              for (int r = 0; r < 4; ++r) {
                float p = (keyb + r <= qg) ? __builtin_amdgcn_exp2f(s[mt][ntl][r]) : 0.f;
                u[r] = __float_as_uint(p);
              }
            }
            u32 lo = (u[0] >> 16) | (u[1] & 0xffff0000u);
            u32 hi = (u[2] >> 16) | (u[3] & 0xffff0000u);
            int uswz = (mt * 2 + (quad >> 1)) ^ (l15 & 3);
            *(u32x2*)&Ps[w][ntl * 16 + l15][uswz * 8 + (quad & 1) * 4] = (u32x2){lo, hi};
          }
        bf16x8 bv[4];
        #pragma unroll
        for (int n = 0; n < 4; ++n)
          bv[n] = *(const bf16x8*)&Vts[cur][n * 16 + l15][((h2 * 4 + quad) ^ sw) * 8];
        __builtin_amdgcn_s_setprio(1);
        #pragma unroll
        for (int ntl = 0; ntl < 2; ++ntl) {
          bf16x8 ap = *(const bf16x8*)&Ps[w][ntl * 16 + l15][(quad ^ (l15 & 3)) * 8];
          o_l[ntl] = __builtin_amdgcn_mfma_f32_16x16x32_bf16(ap, ones, o_l[ntl], 0, 0, 0);
          #pragma unroll
          for (int n = 0; n < 4; ++n)
            o[ntl][n] = __builtin_amdgcn_mfma_f32_16x16x32_bf16(ap, bv[n], o[ntl][n], 0, 0, 0);
        }
        __builtin_amdgcn_s_setprio(0);
      }
    }

    #pragma unroll
    for (int ntl = 0; ntl < 2; ++ntl) {
      #pragma unroll
      for (int r = 0; r < 4; ++r) {
        float inv = __builtin_amdgcn_rcpf(o_l[ntl][r]);
        int qg = qb0 + w * 32 + ntl * 16 + quad * 4 + r;
        us16* dst = ctx + ((size_t)b_ * NS + qg) * ND + h_ * NDH;
        #pragma unroll
        for (int n = 0; n < 4; ++n)
          dst[n * 16 + l15] = f2bf(o[ntl][n][r] * inv);
      }
    }
  }
}

extern "C" void kernel_launch(void* const* d_in, const int* in_sizes, int n_in,
                              void* d_out, int out_size, void* d_ws, size_t ws_size,
                              hipStream_t stream) {
  const float* q  = (const float*)d_in[0];
  const float* k  = (const float*)d_in[1];
  const float* v  = (const float*)d_in[2];
  // d_in[3] = mask (causal by construction)
  const float* wq = (const float*)d_in[4];
  const float* bq_ = (const float*)d_in[5];
  const float* wk = (const float*)d_in[6];
  const float* bk_ = (const float*)d_in[7];
  const float* wv = (const float*)d_in[8];
  const float* bv_ = (const float*)d_in[9];
  const float* wo = (const float*)d_in[10];
  const float* bo_ = (const float*)d_in[11];

  us16* ws = (us16*)d_ws;
  us16* qb  = ws;
  us16* kb  = ws + (size_t)E_;
  us16* vb  = ws + (size_t)2 * E_;     // later reused as ctx
  us16* wqb = ws + (size_t)3 * E_;
  us16* wkb = wqb + W_;
  us16* wvb = wkb + W_;
  us16* wob = wvb + W_;
  us16* KhF = wob + W_;                // fused-path K output (fresh region)
  us16* ctx = vb;
  us16* Vht = (us16*)d_out;            // d_out scratch: dead before gemm_out
  us16* Qh  = (us16*)d_out + (size_t)E_;

  const float qscale = 0.125f * 1.44269504088896340736f;  // 1/sqrt(DH)*log2(e)
  const bool fused = ws_size >= ((size_t)4 * E_ + 4 * W_) * 2;

  conv_bf16<<<28672, 256, 0, stream>>>(q, k, v, wq, wk, wv, wo,
                                       qb, kb, vb, wqb, wkb, wvb, wob);
  if (fused) {
    gemm_proj9<<<dim3(32, 8, 3), 256, 0, stream>>>(
        qb, kb, vb, wqb, wkb, wvb, bq_, bk_, bv_, Qh, KhF, Vht, qscale, 0, 1, 2);
    attn<<<512, 256, 0, stream>>>(Qh, KhF, Vht, ctx);
  } else {
    gemm_proj9<<<dim3(32, 8, 2), 256, 0, stream>>>(
        qb, vb, vb, wqb, wvb, wvb, bq_, bv_, bv_, Qh, Vht, Vht, qscale, 0, 2, 2);
    gemm_proj9<<<dim3(32, 8, 1), 256, 0, stream>>>(
        kb, kb, kb, wkb, wkb, wkb, bk_, bk_, bk_, qb, qb, qb, qscale, 1, 1, 1);
    attn<<<512, 256, 0, stream>>>(Qh, qb, Vht, ctx);
  }
  gemm_out9<<<dim3(32, 8), 256, 0, stream>>>(ctx, wob, bo_, (float*)d_out);
}

// Round 5
// 297.817 us; speedup vs baseline: 1.1108x; 1.1108x over previous
//
#include <hip/hip_runtime.h>
#include <hip/hip_bf16.h>

#define NB 4
#define NS 2048
#define ND 1024
#define NH 16
#define NDH 64
#define E_ 8388608   // NB*NS*ND
#define W_ 1048576   // ND*ND

typedef __attribute__((ext_vector_type(8))) __bf16 bf16x8;
typedef __attribute__((ext_vector_type(4))) float f32x4;
typedef __attribute__((ext_vector_type(2))) unsigned int u32x2;
typedef unsigned short us16;
typedef unsigned int u32;

__device__ __forceinline__ unsigned short f2bf(float f) {
  union { float f; unsigned u; } v; v.f = f;
  unsigned r = v.u + 0x7FFFu + ((v.u >> 16) & 1u);
  return (unsigned short)(r >> 16);
}

typedef const __attribute__((address_space(1))) unsigned int* gas_t;
typedef __attribute__((address_space(3))) unsigned int* las_t;
__device__ __forceinline__ void gl2lds16(const void* g, void* l) {
  __builtin_amdgcn_global_load_lds((gas_t)g, (las_t)l, 16, 0, 0);
}

// ---------------------------------------------------------------------------
// fp32 -> bf16 conversion pass
// ---------------------------------------------------------------------------
__global__ __launch_bounds__(256) void conv_bf16(
    const float* __restrict__ q, const float* __restrict__ k, const float* __restrict__ v,
    const float* __restrict__ wq, const float* __restrict__ wk, const float* __restrict__ wv,
    const float* __restrict__ wo,
    us16* __restrict__ qb, us16* __restrict__ kb, us16* __restrict__ vb,
    us16* __restrict__ wqb, us16* __restrict__ wkb, us16* __restrict__ wvb,
    us16* __restrict__ wob)
{
  int b = blockIdx.x;
  int seg, off;
  if (b < 24576) { seg = b >> 13; off = b & 8191; }
  else { b -= 24576; seg = 3 + (b >> 10); off = b & 1023; }
  const float* s; us16* d;
  switch (seg) {
    case 0: s = q;  d = qb;  break;
    case 1: s = k;  d = kb;  break;
    case 2: s = v;  d = vb;  break;
    case 3: s = wq; d = wqb; break;
    case 4: s = wk; d = wkb; break;
    case 5: s = wv; d = wvb; break;
    default: s = wo; d = wob; break;
  }
  size_t idx = ((size_t)off * 256 + threadIdx.x) * 4;
  float4 f = *(const float4*)(s + idx);
  ushort4 u;
  u.x = f2bf(f.x); u.y = f2bf(f.y); u.z = f2bf(f.z); u.w = f2bf(f.w);
  *(ushort4*)(d + idx) = u;
}

// ---------------------------------------------------------------------------
// Projection GEMM (bf16), R1-proven 2-barrier structure: Y = X @ W^T + bias.
// 128x128 tile, 4 waves (64x64 each), 3 blocks/CU (implicit cross-block
// overlap per m114 -- hand pipelines at 2 blocks/CU measured SLOWER, R3/R4).
// seg 0: Q plain [B,S,D] scaled; seg 1: K plain [B,S,D]; seg 2: V -> [B,H,DH,S].
// ---------------------------------------------------------------------------
__global__ __launch_bounds__(256, 3) void gemm_proj3(
    const us16* __restrict__ A0, const us16* __restrict__ A1, const us16* __restrict__ A2,
    const us16* __restrict__ W0, const us16* __restrict__ W1, const us16* __restrict__ W2,
    const float* __restrict__ b0, const float* __restrict__ b1, const float* __restrict__ b2,
    us16* __restrict__ o0, us16* __restrict__ o1, us16* __restrict__ o2,
    float qscale, int s0, int s1, int s2)
{
  const int seg = (blockIdx.z == 0) ? s0 : (blockIdx.z == 1) ? s1 : s2;
  const us16* A  = (blockIdx.z == 0) ? A0 : (blockIdx.z == 1) ? A1 : A2;
  const us16* Wt = (blockIdx.z == 0) ? W0 : (blockIdx.z == 1) ? W1 : W2;
  const float* bias = (blockIdx.z == 0) ? b0 : (blockIdx.z == 1) ? b1 : b2;
  us16* out = (blockIdx.z == 0) ? o0 : (blockIdx.z == 1) ? o1 : o2;
  const float scale = (seg == 0) ? qscale : 1.0f;

  __shared__ us16 As[128][64];
  __shared__ us16 Bs[128][64];
  const int tid = threadIdx.x;
  const int lane = tid & 63;
  const int w = tid >> 6;
  const int l15 = lane & 15, quad = lane >> 4;
  const int sw = l15 & 7;
  const int rowBase = blockIdx.x * 128, colBase = blockIdx.y * 128;
  const int srow = w * 32 + (lane >> 3);
  const int cu = (lane & 7) ^ ((lane >> 3) & 7);
  const us16* ga = A  + (size_t)(rowBase + srow) * ND + cu * 8;
  const us16* gb = Wt + (size_t)(colBase + srow) * ND + cu * 8;
  const int wr = (w >> 1) * 64, wc = (w & 1) * 64;

  f32x4 acc[4][4] = {};
  for (int kt = 0; kt < ND; kt += 64) {
    __syncthreads();
    #pragma unroll
    for (int c = 0; c < 4; ++c) {
      gl2lds16(ga + kt + c * 8 * ND, &As[w * 32 + c * 8][0]);
      gl2lds16(gb + kt + c * 8 * ND, &Bs[w * 32 + c * 8][0]);
    }
    __syncthreads();
    #pragma unroll
    for (int ks = 0; ks < 2; ++ks) {
      bf16x8 af[4], bfr[4];
      #pragma unroll
      for (int i = 0; i < 4; ++i)
        af[i]  = *(const bf16x8*)&As[wr + i * 16 + l15][((ks * 4 + quad) ^ sw) * 8];
      #pragma unroll
      for (int j = 0; j < 4; ++j)
        bfr[j] = *(const bf16x8*)&Bs[wc + j * 16 + l15][((ks * 4 + quad) ^ sw) * 8];
      #pragma unroll
      for (int i = 0; i < 4; ++i)
        #pragma unroll
        for (int j = 0; j < 4; ++j)
          acc[i][j] = __builtin_amdgcn_mfma_f32_16x16x32_bf16(af[i], bfr[j], acc[i][j], 0, 0, 0);
    }
  }

  if (seg < 2) {
    #pragma unroll
    for (int i = 0; i < 4; ++i) {
      #pragma unroll
      for (int j = 0; j < 4; ++j) {
        int colg = colBase + wc + j * 16 + l15;
        float bval = bias[colg];
        #pragma unroll
        for (int r = 0; r < 4; ++r) {
          int rowg = rowBase + wr + i * 16 + quad * 4 + r;
          out[(size_t)rowg * ND + colg] = f2bf((acc[i][j][r] + bval) * scale);
        }
      }
    }
  } else {
    #pragma unroll
    for (int i = 0; i < 4; ++i) {
      #pragma unroll
      for (int j = 0; j < 4; ++j) {
        int colg = colBase + wc + j * 16 + l15;
        float bval = bias[colg];
        int h_ = colg >> 6, d_ = colg & 63;
        int rowg0 = rowBase + wr + i * 16 + quad * 4;
        int b_ = rowg0 >> 11, sr0 = rowg0 & (NS - 1);
        ushort4 vv;
        vv.x = f2bf(acc[i][j][0] + bval);
        vv.y = f2bf(acc[i][j][1] + bval);
        vv.z = f2bf(acc[i][j][2] + bval);
        vv.w = f2bf(acc[i][j][3] + bval);
        *(ushort4*)(out + ((size_t)(b_ * NH + h_) * NDH + d_) * NS + sr0) = vv;
      }
    }
  }
}

// ---------------------------------------------------------------------------
// Flash attention, causal, fixed-max softmax (exp2 domain; scale folded in Q).
// R5: 8 waves x 16 q-rows (512 thr) instead of 4 x 32 -- halves per-wave work
// per key-tile iteration and doubles waves/SIMD to 4 (2 blocks/CU, 72KB LDS)
// to cover the per-iteration barrier/staging stall (pipes were ~57% busy at
// 2 waves/SIMD). Same KVBLK=128 double-buffer, diagonal skip, setprio.
// ---------------------------------------------------------------------------
__global__ __launch_bounds__(512, 2) void attn(
    const us16* __restrict__ Qh, const us16* __restrict__ Kh,
    const us16* __restrict__ Vht, us16* __restrict__ ctx)
{
  __shared__ us16 Ks[2][128][64];    // K tile: 128 keys x 64 d (128B rows, 8-slot XOR)
  __shared__ us16 Vts[2][64][128];   // V^T tile: 64 d x 128 keys
  __shared__ us16 Ps[8][16][32];     // per-wave P scratch (64B rows)
  us16* Qsta = &Vts[1][0][0];        // Q staging overlays buf1 (16KB exact)

  const int bh = blockIdx.x & 63;    // %8 XCD round-robin: same head -> same XCD
  const int pr = blockIdx.x >> 6;    // 0..7
  const int b_ = bh >> 4, h_ = bh & 15;
  const int tid = threadIdx.x, lane = tid & 63, w = tid >> 6;  // w: 0..7
  const int l15 = lane & 15, quad = lane >> 4;
  const int sw = l15 & 7;
  const int lr8 = lane >> 3;
  const int cu = (lane & 7) ^ (lr8 & 7);
  // V staging lane map: 4 rows x 16 slots per 1KB gl2lds chunk
  const int vr = lane >> 4;          // row within 4-row group
  const int vs = lane & 15;          // 16B slot (16 per 128-key row)
  const int cs0 = (vs & 8) | ((vs & 7) ^ vr);         // d&7 == vr   (rows w*8+vr)
  const int cs1 = (vs & 8) | ((vs & 7) ^ (vr | 4));   // d&7 == vr+4 (rows w*8+4+vr)

  bf16x8 ones;
  #pragma unroll
  for (int i = 0; i < 8; ++i) ones[i] = (__bf16)1.0f;

  const us16* gk  = Kh  + ((size_t)b_ * NS + w * 16 + lr8) * ND + h_ * NDH + cu * 8;
  const us16* gv0 = Vht + ((size_t)bh * NDH + w * 8 + vr) * NS + cs0 * 8;
  const us16* gv1 = Vht + ((size_t)bh * NDH + w * 8 + 4 + vr) * NS + cs1 * 8;

  for (int pass = 0; pass < 2; ++pass) {
    const int tq = pass ? (15 - pr) : pr;
    const int qb0 = tq * 128;
    const int nt = tq + 1;             // 128-key tiles needed (causal)
    const int qw = qb0 + w * 16;       // this wave's 16 q-rows

    __syncthreads();   // previous pass fully done with LDS
    {
      const us16* gq = Qh + ((size_t)b_ * NS + qb0 + w * 16 + lr8) * ND + h_ * NDH + cu * 8;
      gl2lds16(gq,                    Qsta + (w * 16) * 64);
      gl2lds16(gq + (size_t)8 * ND,   Qsta + (w * 16 + 8) * 64);
    }
    // prefetch tile 0 -> buffer 0, overlapped with Q staging
    gl2lds16(gk,            &Ks[0][w * 16][0]);
    gl2lds16(gk + 8 * ND,   &Ks[0][w * 16 + 8][0]);
    gl2lds16(gv0,           &Vts[0][w * 8][0]);
    gl2lds16(gv1,           &Vts[0][w * 8 + 4][0]);
    __syncthreads();   // Q + tile 0 landed
    bf16x8 bq[2];
    #pragma unroll
    for (int c = 0; c < 2; ++c)
      bq[c] = *(const bf16x8*)(Qsta + (w * 16 + l15) * 64 + (((c * 4 + quad) ^ sw) * 8));

    f32x4 o[4] = {};
    f32x4 o_l = {};

    for (int it = 0; it < nt; ++it) {
      const int kb = it * 128;
      const int cur = it & 1;
      __syncthreads();   // it=0: bq reads done everywhere; it>0: tile staged + prev compute done
      if (it + 1 < nt) {
        const int nxt = cur ^ 1;
        const int kn = kb + 128;
        gl2lds16(gk + (size_t)kn * ND,        &Ks[nxt][w * 16][0]);
        gl2lds16(gk + (size_t)(kn + 8) * ND,  &Ks[nxt][w * 16 + 8][0]);
        gl2lds16(gv0 + kn,                    &Vts[nxt][w * 8][0]);
        gl2lds16(gv1 + kn,                    &Vts[nxt][w * 8 + 4][0]);
      }
      #pragma unroll
      for (int h2 = 0; h2 < 4; ++h2) {
        const int keyb0 = kb + h2 * 32;
        if (keyb0 > qw + 15) continue;   // beyond this wave's diagonal
        const bool full = (keyb0 + 31 <= qw);
        f32x4 s[2];
        __builtin_amdgcn_s_setprio(1);
        #pragma unroll
        for (int mt = 0; mt < 2; ++mt) {
          bf16x8 ak0 = *(const bf16x8*)&Ks[cur][h2 * 32 + mt * 16 + l15][(quad ^ sw) * 8];
          bf16x8 ak1 = *(const bf16x8*)&Ks[cur][h2 * 32 + mt * 16 + l15][((4 + quad) ^ sw) * 8];
          f32x4 t = {};
          t = __builtin_amdgcn_mfma_f32_16x16x32_bf16(ak0, bq[0], t, 0, 0, 0);
          t = __builtin_amdgcn_mfma_f32_16x16x32_bf16(ak1, bq[1], t, 0, 0, 0);
          s[mt] = t;
        }
        __builtin_amdgcn_s_setprio(0);
        #pragma unroll
        for (int mt = 0; mt < 2; ++mt) {
          u32 u[4];
          if (full) {
            #pragma unroll
            for (int r = 0; r < 4; ++r)
              u[r] = __float_as_uint(__builtin_amdgcn_exp2f(s[mt][r]));
          } else {
            const int keyb = keyb0 + mt * 16 + quad * 4;
            const int qg = qw + l15;
            #pragma unroll
            for (int r = 0; r < 4; ++r) {
              float p = (keyb + r <= qg) ? __builtin_amdgcn_exp2f(s[mt][r]) : 0.f;
              u[r] = __float_as_uint(p);
            }
          }
          u32 lo = (u[0] >> 16) | (u[1] & 0xffff0000u);
          u32 hi = (u[2] >> 16) | (u[3] & 0xffff0000u);
          int uswz = (mt * 2 + (quad >> 1)) ^ (l15 & 3);
          *(u32x2*)&Ps[w][l15][uswz * 8 + (quad & 1) * 4] = (u32x2){lo, hi};
        }
        bf16x8 bv[4];
        #pragma unroll
        for (int n = 0; n < 4; ++n)
          bv[n] = *(const bf16x8*)&Vts[cur][n * 16 + l15][((h2 * 4 + quad) ^ sw) * 8];
        __builtin_amdgcn_s_setprio(1);
        {
          bf16x8 ap = *(const bf16x8*)&Ps[w][l15][(quad ^ (l15 & 3)) * 8];
          o_l = __builtin_amdgcn_mfma_f32_16x16x32_bf16(ap, ones, o_l, 0, 0, 0);
          #pragma unroll
          for (int n = 0; n < 4; ++n)
            o[n] = __builtin_amdgcn_mfma_f32_16x16x32_bf16(ap, bv[n], o[n], 0, 0, 0);
        }
        __builtin_amdgcn_s_setprio(0);
      }
    }

    #pragma unroll
    for (int r = 0; r < 4; ++r) {
      float inv = __builtin_amdgcn_rcpf(o_l[r]);
      int qg = qb0 + w * 16 + quad * 4 + r;
      us16* dst = ctx + ((size_t)b_ * NS + qg) * ND + h_ * NDH;
      #pragma unroll
      for (int n = 0; n < 4; ++n)
        dst[n * 16 + l15] = f2bf(o[n][r] * inv);
    }
  }
}

// ---------------------------------------------------------------------------
// Output projection (R1-proven): out = ctx(bf16) @ wo^T(bf16) + bo, fp32
// ---------------------------------------------------------------------------
__global__ __launch_bounds__(256, 3) void gemm_out(
    const us16* __restrict__ A, const us16* __restrict__ Wt,
    const float* __restrict__ bias, float* __restrict__ out)
{
  __shared__ us16 As[128][64];
  __shared__ us16 Bs[128][64];
  const int tid = threadIdx.x;
  const int lane = tid & 63;
  const int w = tid >> 6;
  const int l15 = lane & 15, quad = lane >> 4;
  const int sw = l15 & 7;
  const int rowBase = blockIdx.x * 128, colBase = blockIdx.y * 128;
  const int srow = w * 32 + (lane >> 3);
  const int cu = (lane & 7) ^ ((lane >> 3) & 7);
  const us16* ga = A  + (size_t)(rowBase + srow) * ND + cu * 8;
  const us16* gb = Wt + (size_t)(colBase + srow) * ND + cu * 8;
  const int wr = (w >> 1) * 64, wc = (w & 1) * 64;

  f32x4 acc[4][4] = {};
  for (int kt = 0; kt < ND; kt += 64) {
    __syncthreads();
    #pragma unroll
    for (int c = 0; c < 4; ++c) {
      gl2lds16(ga + kt + c * 8 * ND, &As[w * 32 + c * 8][0]);
      gl2lds16(gb + kt + c * 8 * ND, &Bs[w * 32 + c * 8][0]);
    }
    __syncthreads();
    #pragma unroll
    for (int ks = 0; ks < 2; ++ks) {
      bf16x8 af[4], bfr[4];
      #pragma unroll
      for (int i = 0; i < 4; ++i)
        af[i]  = *(const bf16x8*)&As[wr + i * 16 + l15][((ks * 4 + quad) ^ sw) * 8];
      #pragma unroll
      for (int j = 0; j < 4; ++j)
        bfr[j] = *(const bf16x8*)&Bs[wc + j * 16 + l15][((ks * 4 + quad) ^ sw) * 8];
      #pragma unroll
      for (int i = 0; i < 4; ++i)
        #pragma unroll
        for (int j = 0; j < 4; ++j)
          acc[i][j] = __builtin_amdgcn_mfma_f32_16x16x32_bf16(af[i], bfr[j], acc[i][j], 0, 0, 0);
    }
  }

  #pragma unroll
  for (int i = 0; i < 4; ++i) {
    #pragma unroll
    for (int j = 0; j < 4; ++j) {
      int colg = colBase + wc + j * 16 + l15;
      float bval = bias[colg];
      #pragma unroll
      for (int r = 0; r < 4; ++r) {
        int rowg = rowBase + wr + i * 16 + quad * 4 + r;
        out[(size_t)rowg * ND + colg] = acc[i][j][r] + bval;
      }
    }
  }
}

extern "C" void kernel_launch(void* const* d_in, const int* in_sizes, int n_in,
                              void* d_out, int out_size, void* d_ws, size_t ws_size,
                              hipStream_t stream) {
  const float* q  = (const float*)d_in[0];
  const float* k  = (const float*)d_in[1];
  const float* v  = (const float*)d_in[2];
  // d_in[3] = mask (causal by construction)
  const float* wq = (const float*)d_in[4];
  const float* bq_ = (const float*)d_in[5];
  const float* wk = (const float*)d_in[6];
  const float* bk_ = (const float*)d_in[7];
  const float* wv = (const float*)d_in[8];
  const float* bv_ = (const float*)d_in[9];
  const float* wo = (const float*)d_in[10];
  const float* bo_ = (const float*)d_in[11];

  us16* ws = (us16*)d_ws;
  us16* qb  = ws;
  us16* kb  = ws + (size_t)E_;
  us16* vb  = ws + (size_t)2 * E_;     // later reused as ctx
  us16* wqb = ws + (size_t)3 * E_;
  us16* wkb = wqb + W_;
  us16* wvb = wkb + W_;
  us16* wob = wvb + W_;
  us16* KhF = wob + W_;                // fused-path K output (fresh region)
  us16* ctx = vb;
  us16* Vht = (us16*)d_out;            // d_out scratch: dead before gemm_out
  us16* Qh  = (us16*)d_out + (size_t)E_;

  const float qscale = 0.125f * 1.44269504088896340736f;  // 1/sqrt(DH)*log2(e)
  const bool fused = ws_size >= ((size_t)4 * E_ + 4 * W_) * 2;

  conv_bf16<<<28672, 256, 0, stream>>>(q, k, v, wq, wk, wv, wo,
                                       qb, kb, vb, wqb, wkb, wvb, wob);
  if (fused) {
    gemm_proj3<<<dim3(64, 8, 3), 256, 0, stream>>>(
        qb, kb, vb, wqb, wkb, wvb, bq_, bk_, bv_, Qh, KhF, Vht, qscale, 0, 1, 2);
    attn<<<512, 512, 0, stream>>>(Qh, KhF, Vht, ctx);
  } else {
    gemm_proj3<<<dim3(64, 8, 2), 256, 0, stream>>>(
        qb, vb, vb, wqb, wvb, wvb, bq_, bv_, bv_, Qh, Vht, Vht, qscale, 0, 2, 2);
    gemm_proj3<<<dim3(64, 8, 1), 256, 0, stream>>>(
        kb, kb, kb, wkb, wkb, wkb, bk_, bk_, bk_, qb, qb, qb, qscale, 1, 1, 1);
    attn<<<512, 512, 0, stream>>>(Qh, qb, Vht, ctx);
  }
  gemm_out<<<dim3(64, 8), 256, 0, stream>>>(ctx, wob, bo_, (float*)d_out);
}